// Round 3
// baseline (45.789 us; speedup 1.0000x reference)
//
#include <hip/hip_runtime.h>
#include <hip/hip_bf16.h>
#include <cstdint>

// VQ-VAE vector quantize: N=65536 vectors, D=64, K=512 codes.
// d_in[0]: inputs fp32 [65536,64], d_in[1]: embeddings fp32 [512,64]
// d_out: [0]=loss, [1..4194304]=latent (gathered fp32 embeddings)

typedef __attribute__((ext_vector_type(8))) short bf16x8;
typedef __attribute__((ext_vector_type(4))) float f32x4;

__device__ __forceinline__ short f2bf(float f) {
    uint32_t u = __builtin_bit_cast(uint32_t, f);
    u += 0x7FFFu + ((u >> 16) & 1u);   // round-to-nearest-even
    return (short)(u >> 16);
}

// ws layout (bytes):
//  [0, 65536)     : B fragments bf16(-e), [ct(32)][ks(2)][lane(64)] x 16B
//  [65536, 67584) : ee[512] fp32 = ||e_k||^2
//  [67584, 69632) : partials[512] fp32
//  [69632, 69636) : completion counter
#define WS_EE   65536
#define WS_PART 67584
#define WS_CTR  69632

// ---------------- Kernel 1: setup (4 blocks x 256) ----------------
// Converts emb once into MFMA-fragment-ordered bf16(-e) + fp32 norms.
__global__ __launch_bounds__(256)
void vq_setup(const float* __restrict__ emb, char* __restrict__ ws) {
    const int tid = threadIdx.x, bid = blockIdx.x;
    bf16x8* bfrag = (bf16x8*)ws;
    float* ee = (float*)(ws + WS_EE);
    if (bid == 0 && tid == 0) *(uint32_t*)(ws + WS_CTR) = 0u;
    #pragma unroll
    for (int k = 0; k < 4; ++k) {
        const int s = bid * 1024 + k * 256 + tid;
        const int ct = s >> 7, ks = (s >> 6) & 1, ln = s & 63;
        const int code = (ct << 4) | (ln & 15);
        const int d0 = ks * 32 + ((ln >> 4) << 3);
        const float* src = emb + code * 64 + d0;
        float4 v0 = *(const float4*)src;
        float4 v1 = *(const float4*)(src + 4);
        bf16x8 b;
        b[0] = f2bf(-v0.x); b[1] = f2bf(-v0.y); b[2] = f2bf(-v0.z); b[3] = f2bf(-v0.w);
        b[4] = f2bf(-v1.x); b[5] = f2bf(-v1.y); b[6] = f2bf(-v1.z); b[7] = f2bf(-v1.w);
        bfrag[s] = b;
    }
    if (tid < 128) {
        const int c = bid * 128 + tid;
        const float4* e4 = (const float4*)(emb + c * 64);
        float s = 0.f;
        #pragma unroll
        for (int q = 0; q < 16; ++q) {
            float4 v = e4[q];
            s = fmaf(v.x, v.x, fmaf(v.y, v.y, fmaf(v.z, v.z, fmaf(v.w, v.w, s))));
        }
        ee[c] = s;
    }
}

// ---------------- Kernel 2: fused main (512 blocks x 256, 2 blocks/CU) -------
// Block owns 128 rows; wave owns 32 rows (2 M-tiles). LDS staged from ws via
// global_load_lds (linear layout == wave-uniform base + lane*16 HW pattern).
__global__ __launch_bounds__(256, 2)
void vq_main(const float* __restrict__ flat, const float* __restrict__ emb,
             char* __restrict__ ws, float* __restrict__ out) {
    __shared__ uint32_t ldsbuf[16896];   // 64 KB bfrag + 2 KB ee
    __shared__ float red[4];
    __shared__ int lastflag;

    const int tid = threadIdx.x, bid = blockIdx.x;
    const int lane = tid & 63, wid = tid >> 6;
    const int rb = bid * 128 + wid * 32;

    // issue A loads first (fp32, full 128B-line efficiency)
    float4 araw[2][2][2];
    #pragma unroll
    for (int mt = 0; mt < 2; ++mt)
        #pragma unroll
        for (int ks = 0; ks < 2; ++ks) {
            const int row = rb + mt * 16 + (lane & 15);
            const float* src = flat + (long)row * 64 + ks * 32 + ((lane >> 4) << 3);
            araw[mt][ks][0] = *(const float4*)src;
            araw[mt][ks][1] = *(const float4*)(src + 4);
        }

    // stage B fragments + ee: 66 KB via global_load_lds width 16
    {
        const char* wsg = (const char*)ws;
        char* ldsb = (char*)ldsbuf;
        #pragma unroll
        for (int i = 0; i < 16; ++i) {
            const int off = i * 4096 + tid * 16;
            __builtin_amdgcn_global_load_lds(
                (const __attribute__((address_space(1))) void*)(wsg + off),
                (__attribute__((address_space(3))) void*)(ldsb + off), 16, 0, 0);
        }
        if (tid < 128) {
            const int off = WS_EE + tid * 16;
            __builtin_amdgcn_global_load_lds(
                (const __attribute__((address_space(1))) void*)(wsg + off),
                (__attribute__((address_space(3))) void*)(ldsb + off), 16, 0, 0);
        }
    }

    // convert A to bf16 while staging is in flight
    bf16x8 a[2][2];
    #pragma unroll
    for (int mt = 0; mt < 2; ++mt)
        #pragma unroll
        for (int ks = 0; ks < 2; ++ks) {
            float4 v0 = araw[mt][ks][0], v1 = araw[mt][ks][1];
            bf16x8 f;
            f[0] = f2bf(v0.x); f[1] = f2bf(v0.y); f[2] = f2bf(v0.z); f[3] = f2bf(v0.w);
            f[4] = f2bf(v1.x); f[5] = f2bf(v1.y); f[6] = f2bf(v1.z); f[7] = f2bf(v1.w);
            a[mt][ks] = f;
        }

    __syncthreads();

    const bf16x8* bfrag = (const bf16x8*)ldsbuf;
    const float* eel = (const float*)ldsbuf + 16384;

    // packed running min: dist/2 in bits 31..9, code index in bits 8..0
    float pm[8];
    #pragma unroll
    for (int i = 0; i < 8; ++i) pm[i] = __builtin_bit_cast(float, 0x7F800000u);

    const int cb = lane & 15;
    for (int ct = 0; ct < 32; ++ct) {
        bf16x8 b0 = bfrag[ct * 128 + lane];
        bf16x8 b1 = bfrag[ct * 128 + 64 + lane];
        const int colv = (ct << 4) | cb;
        const float h = 0.5f * eel[colv];
        #pragma unroll
        for (int mt = 0; mt < 2; ++mt) {
            f32x4 acc = {h, h, h, h};        // acc = 0.5||e||^2 - x.e  (B = -e)
            acc = __builtin_amdgcn_mfma_f32_16x16x32_bf16(a[mt][0], b0, acc, 0, 0, 0);
            acc = __builtin_amdgcn_mfma_f32_16x16x32_bf16(a[mt][1], b1, acc, 0, 0, 0);
            #pragma unroll
            for (int j = 0; j < 4; ++j) {
                uint32_t dp = (__builtin_bit_cast(uint32_t, acc[j]) & 0xFFFFFE00u) | (uint32_t)colv;
                float fd = __builtin_bit_cast(float, dp);
                pm[mt * 4 + j] = fminf(pm[mt * 4 + j], fd);
            }
        }
    }

    // butterfly min over the 16 column-class lanes
    #pragma unroll
    for (int m = 1; m < 16; m <<= 1) {
        #pragma unroll
        for (int i = 0; i < 8; ++i)
            pm[i] = fminf(pm[i], __shfl_xor(pm[i], m, 64));
    }

    // broadcast winning code of each of the wave's 32 rows
    int idxr[32];
    #pragma unroll
    for (int r = 0; r < 32; ++r) {
        const int mt = r >> 4, g = (r >> 2) & 3, j = r & 3;
        float v = __shfl(pm[mt * 4 + j], g << 4, 64);
        idxr[r] = (int)(__builtin_bit_cast(uint32_t, v) & 0x1FFu);
    }

    // epilogue: gather fp32 emb (L2-hit) + coalesced latent store + loss acc;
    // x re-read hits L2 (block's 32 KB of flat resident).
    float accL = 0.f;
    float* ob = out + 1 + (long)rb * 64;
    #pragma unroll 8
    for (int it = 0; it < 32; ++it) {
        float ev = emb[idxr[it] * 64 + lane];
        float xv = flat[(long)(rb + it) * 64 + lane];
        ob[it * 64 + lane] = ev;
        float df = ev - xv;
        accL = fmaf(df, df, accL);
    }
    #pragma unroll
    for (int m = 32; m; m >>= 1) accL += __shfl_down(accL, m, 64);
    if (lane == 0) red[wid] = accL;
    __syncthreads();

    // last-block finish: device-scope release/acquire, deterministic sum order
    float* part = (float*)(ws + WS_PART);
    if (tid == 0) {
        float s = red[0] + red[1] + red[2] + red[3];
        __hip_atomic_store(part + bid, s, __ATOMIC_RELEASE, __HIP_MEMORY_SCOPE_AGENT);
        uint32_t old = __hip_atomic_fetch_add((uint32_t*)(ws + WS_CTR), 1u,
                                              __ATOMIC_ACQ_REL, __HIP_MEMORY_SCOPE_AGENT);
        lastflag = (old == 511u);
    }
    __syncthreads();
    if (lastflag && wid == 0) {
        float acc = 0.f;
        #pragma unroll
        for (int i = 0; i < 8; ++i)
            acc += __hip_atomic_load(part + i * 64 + lane, __ATOMIC_ACQUIRE,
                                     __HIP_MEMORY_SCOPE_AGENT);
        #pragma unroll
        for (int m = 32; m; m >>= 1) acc += __shfl_down(acc, m, 64);
        // loss = 0.25*e_loss + q_loss = 1.25 * mse (forward)
        if (lane == 0) out[0] = 1.25f * acc / 4194304.0f;
    }
}

extern "C" void kernel_launch(void* const* d_in, const int* in_sizes, int n_in,
                              void* d_out, int out_size, void* d_ws, size_t ws_size,
                              hipStream_t stream) {
    const float* flat = (const float*)d_in[0];   // [65536,64]
    const float* emb  = (const float*)d_in[1];   // [512,64]
    float* out = (float*)d_out;
    char* ws = (char*)d_ws;

    vq_setup<<<4, 256, 0, stream>>>(emb, ws);
    vq_main<<<512, 256, 0, stream>>>(flat, emb, ws, out);
}

// Round 4
// 25.057 us; speedup vs baseline: 1.8274x; 1.8274x over previous
//
#include <hip/hip_runtime.h>
#include <hip/hip_bf16.h>
#include <cstdint>

// VQ-VAE vector quantize: N=65536 vectors, D=64, K=512 codes.
// d_in[0]: inputs fp32 [65536,64], d_in[1]: embeddings fp32 [512,64]
// d_out: [0]=loss, [1..4194304]=latent (gathered fp32 embeddings)

typedef __attribute__((ext_vector_type(8))) short bf16x8;
typedef __attribute__((ext_vector_type(4))) float f32x4;

__device__ __forceinline__ short f2bf(float f) {
    uint32_t u = __builtin_bit_cast(uint32_t, f);
    u += 0x7FFFu + ((u >> 16) & 1u);   // round-to-nearest-even
    return (short)(u >> 16);
}

// ws layout (bytes):
//  [0, 65536)     : B fragments bf16(-e), [ct(32)][ks(2)][lane(64)] x 16B
//  [65536, 67584) : ee[512] fp32 = ||e_k||^2
//  [67584, 71680) : partials[1024] fp32
#define WS_EE   65536
#define WS_PART 67584

// ---------------- Kernel 1: setup (4 blocks x 256) ----------------
// Converts emb once into MFMA-fragment-ordered bf16(-e) + fp32 norms.
__global__ __launch_bounds__(256)
void vq_setup(const float* __restrict__ emb, char* __restrict__ ws) {
    const int tid = threadIdx.x, bid = blockIdx.x;
    bf16x8* bfrag = (bf16x8*)ws;
    float* ee = (float*)(ws + WS_EE);
    #pragma unroll
    for (int k = 0; k < 4; ++k) {
        const int s = bid * 1024 + k * 256 + tid;
        const int ct = s >> 7, ks = (s >> 6) & 1, ln = s & 63;
        const int code = (ct << 4) | (ln & 15);
        const int d0 = ks * 32 + ((ln >> 4) << 3);
        const float* src = emb + code * 64 + d0;
        float4 v0 = *(const float4*)src;
        float4 v1 = *(const float4*)(src + 4);
        bf16x8 b;
        b[0] = f2bf(-v0.x); b[1] = f2bf(-v0.y); b[2] = f2bf(-v0.z); b[3] = f2bf(-v0.w);
        b[4] = f2bf(-v1.x); b[5] = f2bf(-v1.y); b[6] = f2bf(-v1.z); b[7] = f2bf(-v1.w);
        bfrag[s] = b;
    }
    if (tid < 128) {
        const int c = bid * 128 + tid;
        const float4* e4 = (const float4*)(emb + c * 64);
        float s = 0.f;
        #pragma unroll
        for (int q = 0; q < 16; ++q) {
            float4 v = e4[q];
            s = fmaf(v.x, v.x, fmaf(v.y, v.y, fmaf(v.z, v.z, fmaf(v.w, v.w, s))));
        }
        ee[c] = s;
    }
}

// ---------------- Kernel 2: fused main (1024 blocks x 256, 4 blocks/CU) -------
// Block owns 64 rows; wave owns 16 rows (1 M-tile). Codebook processed in two
// 256-code passes through a 32 KB LDS buffer -> ~34 KB LDS, 16 waves/CU.
__global__ __launch_bounds__(256, 4)
void vq_main(const float* __restrict__ flat, const float* __restrict__ emb,
             char* __restrict__ ws, float* __restrict__ out) {
    __shared__ bf16x8 lbuf[2048];   // 32 KB: 16 tiles x 2 ks x 64 lanes
    __shared__ float  eel[512];     // 2 KB
    __shared__ float  red[4];

    const int tid = threadIdx.x, bid = blockIdx.x;
    const int lane = tid & 63, wid = tid >> 6;
    const int rb = bid * 64 + wid * 16;   // wave's first row

    // A fragments: 1 M-tile x 2 k-steps; issue loads, convert while staging
    const int arow = rb + (lane & 15);
    const float* asrc = flat + (long)arow * 64 + ((lane >> 4) << 3);
    float4 a00 = *(const float4*)asrc;
    float4 a01 = *(const float4*)(asrc + 4);
    float4 a10 = *(const float4*)(asrc + 32);
    float4 a11 = *(const float4*)(asrc + 36);

    // stage ee[512] (2 KB)
    {
        const float4* eg = (const float4*)(ws + WS_EE);
        float4 v = eg[tid >> 1];
        // 2 threads per float4: thread writes 2 floats
        ((float2*)eel)[tid] = (tid & 1) ? make_float2(v.z, v.w) : make_float2(v.x, v.y);
    }

    bf16x8 a[2];
    {
        bf16x8 f;
        f[0] = f2bf(a00.x); f[1] = f2bf(a00.y); f[2] = f2bf(a00.z); f[3] = f2bf(a00.w);
        f[4] = f2bf(a01.x); f[5] = f2bf(a01.y); f[6] = f2bf(a01.z); f[7] = f2bf(a01.w);
        a[0] = f;
        f[0] = f2bf(a10.x); f[1] = f2bf(a10.y); f[2] = f2bf(a10.z); f[3] = f2bf(a10.w);
        f[4] = f2bf(a11.x); f[5] = f2bf(a11.y); f[6] = f2bf(a11.z); f[7] = f2bf(a11.w);
        a[1] = f;
    }

    // packed running min: dist/2 in bits 31..9, code index in bits 8..0
    float pm[4];
    #pragma unroll
    for (int i = 0; i < 4; ++i) pm[i] = __builtin_bit_cast(float, 0x7F800000u);

    const int cb = lane & 15;
    const bf16x8* wsb = (const bf16x8*)ws;

    #pragma unroll
    for (int p = 0; p < 2; ++p) {
        if (p) __syncthreads();             // all waves done with prev pass
        // stage 32 KB: linear copy, 8 x 16B per thread
        #pragma unroll
        for (int k = 0; k < 8; ++k)
            lbuf[k * 256 + tid] = wsb[p * 2048 + k * 256 + tid];
        __syncthreads();

        for (int ctl = 0; ctl < 16; ++ctl) {
            bf16x8 b0 = lbuf[ctl * 128 + lane];
            bf16x8 b1 = lbuf[ctl * 128 + 64 + lane];
            const int colv = ((p * 16 + ctl) << 4) | cb;
            const float h = 0.5f * eel[colv];
            f32x4 acc = {h, h, h, h};        // acc = 0.5||e||^2 - x.e  (B = -e)
            acc = __builtin_amdgcn_mfma_f32_16x16x32_bf16(a[0], b0, acc, 0, 0, 0);
            acc = __builtin_amdgcn_mfma_f32_16x16x32_bf16(a[1], b1, acc, 0, 0, 0);
            #pragma unroll
            for (int j = 0; j < 4; ++j) {
                uint32_t dp = (__builtin_bit_cast(uint32_t, acc[j]) & 0xFFFFFE00u) | (uint32_t)colv;
                float fd = __builtin_bit_cast(float, dp);
                pm[j] = fminf(pm[j], fd);
            }
        }
    }

    // butterfly min over the 16 column-class lanes
    #pragma unroll
    for (int m = 1; m < 16; m <<= 1) {
        #pragma unroll
        for (int i = 0; i < 4; ++i)
            pm[i] = fminf(pm[i], __shfl_xor(pm[i], m, 64));
    }

    // broadcast winning code of each of the wave's 16 rows
    int idxr[16];
    #pragma unroll
    for (int r = 0; r < 16; ++r) {
        float v = __shfl(pm[r & 3], (r >> 2) << 4, 64);
        idxr[r] = (int)(__builtin_bit_cast(uint32_t, v) & 0x1FFu);
    }

    // epilogue: gather fp32 emb (L2-resident) + coalesced latent store + loss;
    // x re-read hits L2 (block's 16 KB of flat resident).
    float accL = 0.f;
    float* ob = out + 1 + (long)rb * 64;
    #pragma unroll 8
    for (int it = 0; it < 16; ++it) {
        float ev = emb[idxr[it] * 64 + lane];
        float xv = flat[(long)(rb + it) * 64 + lane];
        ob[it * 64 + lane] = ev;
        float df = ev - xv;
        accL = fmaf(df, df, accL);
    }
    #pragma unroll
    for (int m = 32; m; m >>= 1) accL += __shfl_down(accL, m, 64);
    if (lane == 0) red[wid] = accL;
    __syncthreads();
    if (tid == 0) {
        float* part = (float*)(ws + WS_PART);
        part[bid] = red[0] + red[1] + red[2] + red[3];
    }
}

// ---------------- Kernel 3: deterministic final reduce ----------------
__global__ __launch_bounds__(256)
void vq_loss(const float* __restrict__ partials, float* __restrict__ out) {
    __shared__ float red[4];
    const int tid = threadIdx.x;
    float acc = partials[tid] + partials[tid + 256] + partials[tid + 512] + partials[tid + 768];
    #pragma unroll
    for (int m = 32; m; m >>= 1) acc += __shfl_down(acc, m, 64);
    if ((tid & 63) == 0) red[tid >> 6] = acc;
    __syncthreads();
    // loss = 0.25*e_loss + q_loss = 1.25 * mse (forward)
    if (tid == 0) out[0] = 1.25f * (red[0] + red[1] + red[2] + red[3]) / 4194304.0f;
}

extern "C" void kernel_launch(void* const* d_in, const int* in_sizes, int n_in,
                              void* d_out, int out_size, void* d_ws, size_t ws_size,
                              hipStream_t stream) {
    const float* flat = (const float*)d_in[0];   // [65536,64]
    const float* emb  = (const float*)d_in[1];   // [512,64]
    float* out = (float*)d_out;
    char* ws = (char*)d_ws;

    vq_setup<<<4, 256, 0, stream>>>(emb, ws);
    vq_main<<<1024, 256, 0, stream>>>(flat, emb, ws, out);
    vq_loss<<<1, 256, 0, stream>>>((const float*)(ws + WS_PART), out);
}